// Round 7
// baseline (1451.698 us; speedup 1.0000x reference)
//
#include <hip/hip_runtime.h>
#include <stdint.h>

#define T_LEN 128
#define BATCH 128
#define DHID 512
#define H 256
#define NTAGS 60
#define START_TAG 58
#define STOP_TAG 59
#define NEGV -10000.0f

typedef __attribute__((ext_vector_type(4))) float floatx4;
typedef __attribute__((ext_vector_type(2))) float floatx2;
typedef __attribute__((ext_vector_type(8))) int v8i;
typedef unsigned short u16;
typedef unsigned char u8;
typedef unsigned int u32;
typedef unsigned long long u64c;

#define SCALE1 0x7F7F7F7F  // E8M0 = 1.0 in every byte

// HW fp8 (e4m3) conversions
__device__ __forceinline__ floatx4 f8x4tof(u32 v) {
  floatx2 lo = __builtin_amdgcn_cvt_pk_f32_fp8((int)v, false);
  floatx2 hi = __builtin_amdgcn_cvt_pk_f32_fp8((int)v, true);
  floatx4 r;
  r[0] = lo[0]; r[1] = lo[1]; r[2] = hi[0]; r[3] = hi[1];
  return r;
}
__device__ __forceinline__ float f8tof(u32 v) {
  floatx2 lo = __builtin_amdgcn_cvt_pk_f32_fp8((int)(v & 0xff), false);
  return lo[0];
}
__device__ __forceinline__ u8 ftof8(float f) {
  return (u8)(__builtin_amdgcn_cvt_pk_fp8_f32(f, f, 0, false) & 0xff);
}
__device__ __forceinline__ u32 pk4f8(float a, float b, float c, float d) {
  int o = __builtin_amdgcn_cvt_pk_fp8_f32(a, b, 0, false);
  o = __builtin_amdgcn_cvt_pk_fp8_f32(c, d, o, true);
  return (u32)o;
}
__device__ __forceinline__ float sigx(float x) {
  float e = __expf(-x);
  return __builtin_amdgcn_rcpf(1.0f + e);
}
__device__ __forceinline__ float tanhx(float x) {
  float e = __expf(-2.0f * x);
  return 2.0f * __builtin_amdgcn_rcpf(1.0f + e) - 1.0f;
}
__device__ __forceinline__ u32 relu8(u32 a) {
  u32 m = (a & 0x80808080u) >> 7;
  m *= 255u;
  return a & ~m;
}
__device__ __forceinline__ u32 reluadd8(u32 a, u32 b) {
  floatx4 av = f8x4tof(relu8(a));
  floatx4 bv = f8x4tof(relu8(b));
  return pk4f8(av[0] + bv[0], av[1] + bv[1], av[2] + bv[2], av[3] + bv[3]);
}
// 32-byte fragment builders
__device__ __forceinline__ v8i frag_pair(uint4 a, uint4 b) {
  union { uint4 q[2]; v8i v; } u;
  u.q[0] = a; u.q[1] = b;
  return u.v;
}
#define MFMA128(a, b, c) \
  __builtin_amdgcn_mfma_scale_f32_16x16x128_f8f6f4((a), (b), (c), 0, 0, 0, SCALE1, 0, SCALE1)

// Raw workgroup barrier: LDS-visibility only (R17/R19/R20-verified). Avoids
// __syncthreads' forced s_waitcnt vmcnt(0), which would serialize in-flight
// global stores/loads into every scan step.
__device__ __forceinline__ void wg_barrier_lds() {
  asm volatile("s_waitcnt lgkmcnt(0)" ::: "memory");
  __builtin_amdgcn_s_barrier();
  __builtin_amdgcn_sched_barrier(0);
}

// ---------------------------------------------------------------------------
// Pack weights -> fp8: whh [7][2][1024][256], wih [6][2][1024][512], fcw [64][512].
// ---------------------------------------------------------------------------
__global__ void pack_kernel(const float* __restrict__ whh1, const float* __restrict__ whh,
                            const float* __restrict__ wih, const float* __restrict__ fcw,
                            u8* __restrict__ whh_f8, u8* __restrict__ wih_f8,
                            u8* __restrict__ fcw_f8) {
  const int n_whh1 = 2 * 1024 * 256;
  const int n_whh  = 6 * 2 * 1024 * 256;
  const int n_wih  = 6 * 2 * 1024 * 512;
  const int n_fcw  = 64 * 512;
  const int total = n_whh1 + n_whh + n_wih + n_fcw;
  for (int i = blockIdx.x * blockDim.x + threadIdx.x; i < total; i += gridDim.x * blockDim.x) {
    if (i < n_whh1) {
      whh_f8[i] = ftof8(whh1[i]);
    } else if (i < n_whh1 + n_whh) {
      whh_f8[i] = ftof8(whh[i - n_whh1]);
    } else if (i < n_whh1 + n_whh + n_wih) {
      int j = i - n_whh1 - n_whh;
      wih_f8[j] = ftof8(wih[j]);
    } else {
      int j = i - n_whh1 - n_whh - n_wih;
      int row = j >> 9;
      fcw_f8[j] = (row < NTAGS) ? ftof8(fcw[j]) : (u8)0;
    }
  }
}

// ---------------------------------------------------------------------------
// Layer-1 xw (Din=3), fp8. Layout: xw[b][t][2048 cols] batch-major (block-
// private, coalesced scan reads).
// ---------------------------------------------------------------------------
__global__ void xw1_kernel(const float* __restrict__ sent, const float* __restrict__ wih1,
                           const float* __restrict__ b1, u8* __restrict__ xw) {
  int u = blockIdx.x * blockDim.x + threadIdx.x;  // 128b * 128t * 512 u32
  int cq = u & 511;
  int t = (u >> 9) & 127;
  int b = u >> 16;
  int col0 = cq * 4;
  const float* x = sent + ((size_t)t * BATCH + b) * 3;
  float x0 = x[0], x1 = x[1], x2 = x[2];
  float o[4];
#pragma unroll
  for (int j = 0; j < 4; ++j) {
    const float* w = wih1 + (size_t)(col0 + j) * 3;
    o[j] = b1[col0 + j] + x0 * w[0] + x1 * w[1] + x2 * w[2];
  }
  *(u32*)(xw + ((size_t)b * T_LEN + t) * 2048 + col0) = pk4f8(o[0], o[1], o[2], o[3]);
}

// ---------------------------------------------------------------------------
// xw GEMM layers 2..7 (plain fp8 K=32 MFMA — measured fastest).
// Epilogue byte-stores into plain xw[b][t][2048] (R16/R19-verified).
// ---------------------------------------------------------------------------
__launch_bounds__(256, 4)
__global__ void gemm_xw_kernel(const u8* __restrict__ cur, const u8* __restrict__ prev,
                               const u8* __restrict__ W, const float* __restrict__ bias,
                               u8* __restrict__ xw) {
  __shared__ __align__(16) u8 As[64][72];
  const int nbase = blockIdx.x * 256;
  const int m0 = blockIdx.y * 64;
  const int tid = threadIdx.x;
  const int wv = tid >> 6, ln = tid & 63;
  const int c16 = ln & 15, q = ln >> 4;
  const int ncol0 = nbase + wv * 64;

  floatx4 acc[4][4];
#pragma unroll
  for (int i = 0; i < 4; ++i)
#pragma unroll
    for (int j = 0; j < 4; ++j) { acc[i][j][0] = 0.f; acc[i][j][1] = 0.f; acc[i][j][2] = 0.f; acc[i][j][3] = 0.f; }

  for (int kc = 0; kc < 8; ++kc) {
    {
      int r = tid >> 2;
      int cb = (tid & 3) * 16;
      size_t g = (size_t)(m0 + r) * DHID + kc * 64 + cb;
      uint4 a4 = *(const uint4*)(cur + g);
      if (prev) {
        uint4 p4 = *(const uint4*)(prev + g);
        a4.x = reluadd8(a4.x, p4.x); a4.y = reluadd8(a4.y, p4.y);
        a4.z = reluadd8(a4.z, p4.z); a4.w = reluadd8(a4.w, p4.w);
      } else {
        a4.x = relu8(a4.x); a4.y = relu8(a4.y);
        a4.z = relu8(a4.z); a4.w = relu8(a4.w);
      }
      u64c lo = ((u64c)a4.y << 32) | a4.x;
      u64c hi = ((u64c)a4.w << 32) | a4.z;
      *(u64c*)(&As[r][cb]) = lo;
      *(u64c*)(&As[r][cb + 8]) = hi;
    }
    __syncthreads();
#pragma unroll
    for (int kt = 0; kt < 2; ++kt) {
      int kg = kc * 64 + kt * 32 + q * 8;
      long bfr[4];
#pragma unroll
      for (int nt = 0; nt < 4; ++nt)
        bfr[nt] = *(const long*)(W + (size_t)(ncol0 + nt * 16 + c16) * DHID + kg);
      long afr[4];
#pragma unroll
      for (int mt = 0; mt < 4; ++mt)
        afr[mt] = *(const long*)(&As[mt * 16 + c16][kt * 32 + q * 8]);
#pragma unroll
      for (int nt = 0; nt < 4; ++nt)
#pragma unroll
        for (int mt = 0; mt < 4; ++mt)
          acc[nt][mt] = __builtin_amdgcn_mfma_f32_16x16x32_fp8_fp8(afr[mt], bfr[nt], acc[nt][mt], 0, 0, 0);
    }
    __syncthreads();
  }
  // m = t*128 + batch; C tile row = mt*16 + 4q + r
  const int t = m0 >> 7;
  const int bb = (m0 & 127);
#pragma unroll
  for (int nt = 0; nt < 4; ++nt) {
    int col = ncol0 + nt * 16 + c16;
    float bv = bias[col];
#pragma unroll
    for (int mt = 0; mt < 4; ++mt) {
      int bbase = bb + mt * 16 + q * 4;
#pragma unroll
      for (int r = 0; r < 4; ++r)
        xw[((size_t)(bbase + r) * T_LEN + t) * 2048 + col] = ftof8(acc[nt][mt][r] + bv);
    }
  }
}

// ---------------------------------------------------------------------------
// LSTM scan R21 = R20 structure (verified) + INTERLEAVED step schedule.
// R20 counters showed phase-locked pipes: both waves/SIMD issue MFMAs
// together (~1040 cyc matrix-busy) then do gate VALU together (~760 cyc) —
// sequential, step 2210 cyc. Fix: chunk the step as {8 MFMA (i,f)} | SB |
// {pre+exp for i,f — stalls on MFMA results, letting the OTHER wave's MFMAs
// fill the matrix pipe} | {8 MFMA (g,o)} | SB | {rest of gate chain}.
// Two waves cover each other's stalls -> target step ~ max(1107, 760) +
// exposed chain. A-frags now 2x ds_read_b128 (conflict-free broadcast).
// ---------------------------------------------------------------------------
__launch_bounds__(512, 2)
__global__ void scan_kernel(const u8* __restrict__ whh, const u8* __restrict__ xw,
                            const float* __restrict__ h0, const float* __restrict__ c0,
                            u8* __restrict__ obuf) {
  __shared__ __align__(16) u8 hbuf[2][256];
  const int b   = blockIdx.x & 127;
  const int dir = blockIdx.x >> 7;
  const int tid = threadIdx.x;
  const int ln = tid & 63;
  const int wv = tid >> 6;              // 0..7
  const int c16 = ln & 15, q = ln >> 4;
  const int ntow = q & 1;
  const int col = wv * 32 + ntow * 16 + c16;   // lane's h-col (q pairs dup)

  // --- W -> B-frags [g][nt][kc]: 16 v8i = 128 regs, opaque-pinned ("+v") ---
  v8i wfr[4][2][2];
#pragma unroll
  for (int g = 0; g < 4; ++g)
#pragma unroll
    for (int nt = 0; nt < 2; ++nt)
#pragma unroll
      for (int kc = 0; kc < 2; ++kc) {
        const u8* p4 = whh + ((size_t)(dir * 1024 + g * 256 + wv * 32 + nt * 16 + c16)) * 256 + kc * 128 + q * 32;
        wfr[g][nt][kc] = frag_pair(*(const uint4*)p4, *(const uint4*)(p4 + 16));
      }
#pragma unroll
  for (int g = 0; g < 4; ++g)
#pragma unroll
    for (int nt = 0; nt < 2; ++nt)
#pragma unroll
      for (int kc = 0; kc < 2; ++kc)
        asm volatile("" : "+v"(wfr[g][nt][kc]));  // opaque def: no remat

  // --- h0 -> hbuf[0]; c state ---
  if (tid < 256) hbuf[0][tid] = ftof8(h0[((size_t)dir * BATCH + b) * H + tid]);
  float creg = c0[((size_t)dir * BATCH + b) * H + col];
  __syncthreads();

  // xw: [b][t][2048], block-private 1 KB per step
  const u8* xwt = xw + ((size_t)b * T_LEN + (dir ? T_LEN - 1 : 0)) * 2048 + dir * 1024;
  const ptrdiff_t xstep = (dir ? -1 : 1) * (ptrdiff_t)2048;
  u8* obt = obuf + ((size_t)(dir ? T_LEN - 1 : 0) * BATCH + b) * DHID + dir * H;
  const ptrdiff_t ostep = (dir ? -1 : 1) * (ptrdiff_t)(BATCH * DHID);

  // prefetch s=0 xw (1 byte per gate per lane)
  u32 xb[4];
#pragma unroll
  for (int g = 0; g < 4; ++g) xb[g] = xwt[g * 256 + col];

  floatx4 z4;
  z4[0] = 0.f; z4[1] = 0.f; z4[2] = 0.f; z4[3] = 0.f;

  for (int s = 0; s < T_LEN; ++s) {
    const int p = s & 1, pn = p ^ 1;

    // A-frags: 2x ds_read_b128 each (broadcast within q-groups, conflict-free)
    const u8* hrow = &hbuf[p][q * 32];
    v8i hfr0 = frag_pair(*(const uint4*)(hrow), *(const uint4*)(hrow + 16));
    v8i hfr1 = frag_pair(*(const uint4*)(hrow + 128), *(const uint4*)(hrow + 144));

    // prefetched xw bytes -> floats; issue next step's prefetch
    float xg0 = f8tof(xb[0]), xg1 = f8tof(xb[1]);
    float xg2 = f8tof(xb[2]), xg3 = f8tof(xb[3]);
    if (s + 1 < T_LEN) {
      const u8* xn = xwt + xstep;
#pragma unroll
      for (int g = 0; g < 4; ++g) xb[g] = xn[g * 256 + col];
    }

    // ---- chunk A: 8 MFMA for gates i,f ----
    floatx4 a00 = MFMA128(hfr0, wfr[0][0][0], z4);
    floatx4 a01 = MFMA128(hfr0, wfr[0][1][0], z4);
    floatx4 a10 = MFMA128(hfr0, wfr[1][0][0], z4);
    floatx4 a11 = MFMA128(hfr0, wfr[1][1][0], z4);
    a00 = MFMA128(hfr1, wfr[0][0][1], a00);
    a01 = MFMA128(hfr1, wfr[0][1][1], a01);
    a10 = MFMA128(hfr1, wfr[1][0][1], a10);
    a11 = MFMA128(hfr1, wfr[1][1][1], a11);
    __builtin_amdgcn_sched_barrier(0);

    // ---- gate VALU for i,f (stalls on chunk-A results; other wave's MFMAs
    //      fill the matrix pipe during the stall) ----
    float pre0 = (ntow ? a01[0] : a00[0]) + xg0;
    float pre1 = (ntow ? a11[0] : a10[0]) + xg1;
    float ei = __expf(-pre0);
    float ef = __expf(-pre1);
    __builtin_amdgcn_sched_barrier(0);

    // ---- chunk B: 8 MFMA for gates g,o ----
    floatx4 a20 = MFMA128(hfr0, wfr[2][0][0], z4);
    floatx4 a21 = MFMA128(hfr0, wfr[2][1][0], z4);
    floatx4 a30 = MFMA128(hfr0, wfr[3][0][0], z4);
    floatx4 a31 = MFMA128(hfr0, wfr[3][1][0], z4);
    a20 = MFMA128(hfr1, wfr[2][0][1], a20);
    a21 = MFMA128(hfr1, wfr[2][1][1], a21);
    a30 = MFMA128(hfr1, wfr[3][0][1], a30);
    a31 = MFMA128(hfr1, wfr[3][1][1], a31);
    __builtin_amdgcn_sched_barrier(0);

    // ---- remaining gate chain ----
    float ig = __builtin_amdgcn_rcpf(1.0f + ei);
    float fg = __builtin_amdgcn_rcpf(1.0f + ef);
    float pre2 = (ntow ? a21[0] : a20[0]) + xg2;
    float pre3 = (ntow ? a31[0] : a30[0]) + xg3;
    float eg = __expf(-2.0f * pre2);
    float gg = 2.0f * __builtin_amdgcn_rcpf(1.0f + eg) - 1.0f;
    float eo = __expf(-pre3);
    float og = __builtin_amdgcn_rcpf(1.0f + eo);
    float cn = fg * creg + ig * gg;
    creg = cn;
    float et = __expf(-2.0f * cn);
    float th = 2.0f * __builtin_amdgcn_rcpf(1.0f + et) - 1.0f;
    u8 hb = ftof8(og * th);
    if (q < 2) {
      hbuf[pn][col] = hb;
      obt[col] = hb;                 // stays in flight across the raw barrier
    }
    wg_barrier_lds();

    xwt += xstep;
    obt += ostep;
  }
}

// ---------------------------------------------------------------------------
// FC: feats[16384][64] = out7(fp8)[16384][512] @ fcw^T + fc_b  (fp8 MFMA)
// ---------------------------------------------------------------------------
__launch_bounds__(256, 4)
__global__ void fc_kernel(const u8* __restrict__ A, const u8* __restrict__ W,
                          const float* __restrict__ fb, float* __restrict__ feats) {
  const int tid = threadIdx.x, wv = tid >> 6, ln = tid & 63;
  const int c16 = ln & 15, q = ln >> 4;
  const int m0 = blockIdx.x * 64 + wv * 16;
  floatx4 acc[4];
#pragma unroll
  for (int i = 0; i < 4; ++i) { acc[i][0] = 0.f; acc[i][1] = 0.f; acc[i][2] = 0.f; acc[i][3] = 0.f; }
#pragma unroll
  for (int kt = 0; kt < 16; ++kt) {
    long a = *(const long*)(A + (size_t)(m0 + c16) * DHID + kt * 32 + q * 8);
#pragma unroll
    for (int nt = 0; nt < 4; ++nt) {
      long b = *(const long*)(W + (size_t)(nt * 16 + c16) * DHID + kt * 32 + q * 8);
      acc[nt] = __builtin_amdgcn_mfma_f32_16x16x32_fp8_fp8(a, b, acc[nt], 0, 0, 0);
    }
  }
#pragma unroll
  for (int nt = 0; nt < 4; ++nt) {
    int n = nt * 16 + c16;
    if (n < NTAGS) {
      float bv = fb[n];
#pragma unroll
      for (int r = 0; r < 4; ++r)
        feats[(size_t)(m0 + q * 4 + r) * 64 + n] = acc[nt][r] + bv;
    }
  }
}

// ---------------------------------------------------------------------------
// CRF R19 (verified): one wave per batch; alpha in registers (lane = tag);
// all Tt values t-invariant -> hoisted to registers; t-loop is pure
// shfl/exp/log register arithmetic, zero LDS ops, zero barriers.
// ---------------------------------------------------------------------------
__launch_bounds__(64, 1)
__global__ void crf_kernel(const float* __restrict__ feats, const float* __restrict__ trans,
                           const int* __restrict__ tags, float* __restrict__ out) {
  __shared__ float Tt[64][65];   // Tt[p][k] = trans[k*60+p], else -1e30
  const int b = blockIdx.x;
  const int ln = threadIdx.x;
  for (int i = ln; i < 64 * 65; i += 64) ((float*)Tt)[i] = -1e30f;
  __syncthreads();
  for (int i = ln; i < 3600; i += 64) Tt[i % 60][i / 60] = trans[i];
  __syncthreads();

  // gold path score
  float gsc = 0.f;
  for (int t = ln; t < T_LEN; t += 64) {
    int tg = tags[t * BATCH + b];
    int pv = (t == 0) ? START_TAG : tags[(t - 1) * BATCH + b];
    gsc += Tt[pv][tg] + feats[(size_t)(t * BATCH + b) * 64 + tg];
  }
#pragma unroll
  for (int off = 32; off > 0; off >>= 1) gsc += __shfl_down(gsc, off);
  if (ln == 0) gsc += Tt[tags[(T_LEN - 1) * BATCH + b]][STOP_TAG];

  // hoist the 7 t-invariant transition values this lane touches
  const float t0k  = Tt[0][ln];
  const float t1k  = Tt[1][ln];
  const float tkm  = Tt[(ln - 1) & 63][ln];
  const float t58k = Tt[58][ln];
  const float tk0  = Tt[ln][0];
  const float tk1  = Tt[ln][1];
  const float tk59 = Tt[ln][59];

  // alpha recurrence, lane = tag (register-only loop)
  float alpha = (ln == START_TAG) ? 0.f : NEGV;
  const float* fbase = feats + (size_t)b * 64 + ln;
  const size_t fstride = (size_t)BATCH * 64;
  float fcur = fbase[0];
  for (int t = 0; t < T_LEN; ++t) {
    float fnext = (t + 1 < T_LEN) ? fbase[(size_t)(t + 1) * fstride] : 0.f;
    // gather needed alphas
    float a0  = __shfl(alpha, 0);
    float a1  = __shfl(alpha, 1);
    float a58 = __shfl(alpha, 58);
    float akm = __shfl(alpha, ln - 1);
    // phase A: sparse 4-term LSE (valid for lanes 2..57)
    float v0 = a0 + t0k;
    float v1 = a1 + t1k;
    float v2 = (ln >= 3) ? (akm + tkm) : -1e30f;
    float v3 = a58 + t58k;
    float mA = fmaxf(fmaxf(v0, v1), fmaxf(v2, v3));
    float sA = ((__expf(v0 - mA) + __expf(v1 - mA)) + __expf(v2 - mA)) + __expf(v3 - mA);
    float nvA = mA + __logf(sA) + fcur;
    // phase B: dense rows 0, 1, 59 (cooperative tree reduce)
    float w0 = alpha + tk0;
    float w1 = alpha + tk1;
    float w2 = alpha + tk59;
    float m0 = w0, m1 = w1, m2 = w2;
#pragma unroll
    for (int off = 32; off > 0; off >>= 1) {
      m0 = fmaxf(m0, __shfl_xor(m0, off));
      m1 = fmaxf(m1, __shfl_xor(m1, off));
      m2 = fmaxf(m2, __shfl_xor(m2, off));
    }
    float e0 = __expf(w0 - m0), e1 = __expf(w1 - m1), e2 = __expf(w2 - m2);
#pragma unroll
    for (int off = 32; off > 0; off >>= 1) {
      e0 += __shfl_xor(e0, off);
      e1 += __shfl_xor(e1, off);
      e2 += __shfl_xor(e2, off);
    }
    float f0 = __shfl(fcur, 0), f1 = __shfl(fcur, 1), f59 = __shfl(fcur, 59);
    float nv;
    if (ln == 0)       nv = m0 + __logf(e0) + f0;
    else if (ln == 1)  nv = m1 + __logf(e1) + f1;
    else if (ln == 59) nv = m2 + __logf(e2) + f59;
    else if (ln == 58 || ln >= 60) nv = -1e30f;
    else               nv = nvA;
    alpha = nv;
    fcur = fnext;
  }

  // logZ = LSE(alpha + trans[STOP][p])
  float v = alpha + tk59;
  float mm = v;
#pragma unroll
  for (int off = 32; off > 0; off >>= 1) mm = fmaxf(mm, __shfl_xor(mm, off));
  float es = __expf(v - mm);
#pragma unroll
  for (int off = 32; off > 0; off >>= 1) es += __shfl_xor(es, off);
  if (ln == 0) out[b] = mm + __logf(es) - gsc;
}

// ---------------------------------------------------------------------------
extern "C" void kernel_launch(void* const* d_in, const int* in_sizes, int n_in,
                              void* d_out, int out_size, void* d_ws, size_t ws_size,
                              hipStream_t stream) {
  (void)in_sizes; (void)n_in; (void)out_size; (void)ws_size;
  const float* sent  = (const float*)d_in[0];
  const int*   tags  = (const int*)d_in[1];
  const float* wih1  = (const float*)d_in[2];
  const float* whh1  = (const float*)d_in[3];
  const float* b1    = (const float*)d_in[4];
  const float* wih   = (const float*)d_in[5];
  const float* whh   = (const float*)d_in[6];
  const float* bias  = (const float*)d_in[7];
  const float* fcw   = (const float*)d_in[8];
  const float* fcb   = (const float*)d_in[9];
  const float* h0    = (const float*)d_in[10];
  const float* c0    = (const float*)d_in[11];
  const float* trans = (const float*)d_in[12];
  float* out = (float*)d_out;

  char* ws = (char*)d_ws;
  size_t off = 0;
  auto alloc = [&](size_t bytes) -> void* {
    void* p = ws + off;
    off = (off + bytes + 255) & ~(size_t)255;
    return p;
  };
  u8* whh_f8 = (u8*)alloc((size_t)7 * 2 * 1024 * 256);
  u8* wih_f8 = (u8*)alloc((size_t)6 * 2 * 1024 * 512);
  u8* fcw_f8 = (u8*)alloc((size_t)64 * 512);
  u8* xw     = (u8*)alloc((size_t)16384 * 2048);
  u8* ob[3];
  for (int i = 0; i < 3; ++i) ob[i] = (u8*)alloc((size_t)16384 * 512);
  float* feats = (float*)alloc((size_t)16384 * 64 * 4);

  hipLaunchKernelGGL(pack_kernel, dim3(4096), dim3(256), 0, stream,
                     whh1, whh, wih, fcw, whh_f8, wih_f8, fcw_f8);
  hipLaunchKernelGGL(xw1_kernel, dim3(32768), dim3(256), 0, stream, sent, wih1, b1, xw);
  hipLaunchKernelGGL(scan_kernel, dim3(256), dim3(512), 0, stream,
                     whh_f8, xw, h0, c0, ob[0]);
  for (int L = 1; L < 7; ++L) {
    const u8* curb = ob[(L - 1) % 3];
    const u8* prevb = (L >= 2) ? ob[(L - 2) % 3] : nullptr;
    hipLaunchKernelGGL(gemm_xw_kernel, dim3(8, 256), dim3(256), 0, stream,
                       curb, prevb, wih_f8 + (size_t)(L - 1) * 2 * 1024 * 512,
                       bias + (size_t)(L - 1) * 2048, xw);
    hipLaunchKernelGGL(scan_kernel, dim3(256), dim3(512), 0, stream,
                       whh_f8 + (size_t)L * 2 * 1024 * 256, xw,
                       h0 + (size_t)L * 2 * 128 * 256, c0 + (size_t)L * 2 * 128 * 256,
                       ob[L % 3]);
  }
  hipLaunchKernelGGL(fc_kernel, dim3(256), dim3(256), 0, stream, ob[0], fcw_f8, fcb, feats);
  hipLaunchKernelGGL(crf_kernel, dim3(128), dim3(64), 0, stream, feats, trans, tags, out);
}

// Round 8
// 1404.029 us; speedup vs baseline: 1.0340x; 1.0340x over previous
//
#include <hip/hip_runtime.h>
#include <stdint.h>

#define T_LEN 128
#define BATCH 128
#define DHID 512
#define H 256
#define NTAGS 60
#define START_TAG 58
#define STOP_TAG 59
#define NEGV -10000.0f

typedef __attribute__((ext_vector_type(4))) float floatx4;
typedef __attribute__((ext_vector_type(2))) float floatx2;
typedef __attribute__((ext_vector_type(8))) int v8i;
typedef unsigned short u16;
typedef unsigned char u8;
typedef unsigned int u32;
typedef unsigned long long u64c;

#define SCALE1 0x7F7F7F7F  // E8M0 = 1.0 in every byte

// HW fp8 (e4m3) conversions
__device__ __forceinline__ floatx4 f8x4tof(u32 v) {
  floatx2 lo = __builtin_amdgcn_cvt_pk_f32_fp8((int)v, false);
  floatx2 hi = __builtin_amdgcn_cvt_pk_f32_fp8((int)v, true);
  floatx4 r;
  r[0] = lo[0]; r[1] = lo[1]; r[2] = hi[0]; r[3] = hi[1];
  return r;
}
__device__ __forceinline__ float f8tof(u32 v) {
  floatx2 lo = __builtin_amdgcn_cvt_pk_f32_fp8((int)(v & 0xff), false);
  return lo[0];
}
__device__ __forceinline__ u8 ftof8(float f) {
  return (u8)(__builtin_amdgcn_cvt_pk_fp8_f32(f, f, 0, false) & 0xff);
}
__device__ __forceinline__ u32 pk4f8(float a, float b, float c, float d) {
  int o = __builtin_amdgcn_cvt_pk_fp8_f32(a, b, 0, false);
  o = __builtin_amdgcn_cvt_pk_fp8_f32(c, d, o, true);
  return (u32)o;
}
__device__ __forceinline__ float sigx(float x) {
  float e = __expf(-x);
  return __builtin_amdgcn_rcpf(1.0f + e);
}
__device__ __forceinline__ float tanhx(float x) {
  float e = __expf(-2.0f * x);
  return 2.0f * __builtin_amdgcn_rcpf(1.0f + e) - 1.0f;
}
__device__ __forceinline__ u32 relu8(u32 a) {
  u32 m = (a & 0x80808080u) >> 7;
  m *= 255u;
  return a & ~m;
}
__device__ __forceinline__ u32 reluadd8(u32 a, u32 b) {
  floatx4 av = f8x4tof(relu8(a));
  floatx4 bv = f8x4tof(relu8(b));
  return pk4f8(av[0] + bv[0], av[1] + bv[1], av[2] + bv[2], av[3] + bv[3]);
}
// 32-byte fragment builders
__device__ __forceinline__ v8i frag_pair(uint4 a, uint4 b) {
  union { uint4 q[2]; v8i v; } u;
  u.q[0] = a; u.q[1] = b;
  return u.v;
}
#define MFMA128(a, b, c) \
  __builtin_amdgcn_mfma_scale_f32_16x16x128_f8f6f4((a), (b), (c), 0, 0, 0, SCALE1, 0, SCALE1)

// Raw workgroup barrier: LDS-visibility only (R17/R19/R20-verified).
__device__ __forceinline__ void wg_barrier_lds() {
  asm volatile("s_waitcnt lgkmcnt(0)" ::: "memory");
  __builtin_amdgcn_s_barrier();
  __builtin_amdgcn_sched_barrier(0);
}

// --- DPP full-wave reductions (VALU pipe, ~10 cyc/level vs ~120 for shfl) ---
// Classic GCN pattern: row_shr 1,2,4,8 then row_bcast15, row_bcast31;
// result lands in lane 63; invalid-source lanes get the identity via `old`.
__device__ __forceinline__ float dpp_max64(float v) {
  int t;
#define DMAXSTEP(CTRL)                                                         \
  t = __builtin_amdgcn_update_dpp(__float_as_int(-1e30f), __float_as_int(v),   \
                                  (CTRL), 0xf, 0xf, false);                    \
  v = fmaxf(v, __int_as_float(t));
  DMAXSTEP(0x111) DMAXSTEP(0x112) DMAXSTEP(0x114) DMAXSTEP(0x118)
  DMAXSTEP(0x142) DMAXSTEP(0x143)
#undef DMAXSTEP
  return __int_as_float(__builtin_amdgcn_readlane(__float_as_int(v), 63));
}
__device__ __forceinline__ float dpp_sum64(float v) {
  int t;
#define DADDSTEP(CTRL)                                                         \
  t = __builtin_amdgcn_update_dpp(__float_as_int(0.0f), __float_as_int(v),     \
                                  (CTRL), 0xf, 0xf, false);                    \
  v = v + __int_as_float(t);
  DADDSTEP(0x111) DADDSTEP(0x112) DADDSTEP(0x114) DADDSTEP(0x118)
  DADDSTEP(0x142) DADDSTEP(0x143)
#undef DADDSTEP
  return __int_as_float(__builtin_amdgcn_readlane(__float_as_int(v), 63));
}

// ---------------------------------------------------------------------------
// Pack weights -> fp8: whh [7][2][1024][256], wih [6][2][1024][512], fcw [64][512].
// ---------------------------------------------------------------------------
__global__ void pack_kernel(const float* __restrict__ whh1, const float* __restrict__ whh,
                            const float* __restrict__ wih, const float* __restrict__ fcw,
                            u8* __restrict__ whh_f8, u8* __restrict__ wih_f8,
                            u8* __restrict__ fcw_f8) {
  const int n_whh1 = 2 * 1024 * 256;
  const int n_whh  = 6 * 2 * 1024 * 256;
  const int n_wih  = 6 * 2 * 1024 * 512;
  const int n_fcw  = 64 * 512;
  const int total = n_whh1 + n_whh + n_wih + n_fcw;
  for (int i = blockIdx.x * blockDim.x + threadIdx.x; i < total; i += gridDim.x * blockDim.x) {
    if (i < n_whh1) {
      whh_f8[i] = ftof8(whh1[i]);
    } else if (i < n_whh1 + n_whh) {
      whh_f8[i] = ftof8(whh[i - n_whh1]);
    } else if (i < n_whh1 + n_whh + n_wih) {
      int j = i - n_whh1 - n_whh;
      wih_f8[j] = ftof8(wih[j]);
    } else {
      int j = i - n_whh1 - n_whh - n_wih;
      int row = j >> 9;
      fcw_f8[j] = (row < NTAGS) ? ftof8(fcw[j]) : (u8)0;
    }
  }
}

// ---------------------------------------------------------------------------
// Layer-1 xw (Din=3), fp8. Layout: xw[b][t][2048 cols] batch-major.
// ---------------------------------------------------------------------------
__global__ void xw1_kernel(const float* __restrict__ sent, const float* __restrict__ wih1,
                           const float* __restrict__ b1, u8* __restrict__ xw) {
  int u = blockIdx.x * blockDim.x + threadIdx.x;  // 128b * 128t * 512 u32
  int cq = u & 511;
  int t = (u >> 9) & 127;
  int b = u >> 16;
  int col0 = cq * 4;
  const float* x = sent + ((size_t)t * BATCH + b) * 3;
  float x0 = x[0], x1 = x[1], x2 = x[2];
  float o[4];
#pragma unroll
  for (int j = 0; j < 4; ++j) {
    const float* w = wih1 + (size_t)(col0 + j) * 3;
    o[j] = b1[col0 + j] + x0 * w[0] + x1 * w[1] + x2 * w[2];
  }
  *(u32*)(xw + ((size_t)b * T_LEN + t) * 2048 + col0) = pk4f8(o[0], o[1], o[2], o[3]);
}

// ---------------------------------------------------------------------------
// xw GEMM layers 2..7 (plain fp8 K=32 MFMA — measured fastest).
// ---------------------------------------------------------------------------
__launch_bounds__(256, 4)
__global__ void gemm_xw_kernel(const u8* __restrict__ cur, const u8* __restrict__ prev,
                               const u8* __restrict__ W, const float* __restrict__ bias,
                               u8* __restrict__ xw) {
  __shared__ __align__(16) u8 As[64][72];
  const int nbase = blockIdx.x * 256;
  const int m0 = blockIdx.y * 64;
  const int tid = threadIdx.x;
  const int wv = tid >> 6, ln = tid & 63;
  const int c16 = ln & 15, q = ln >> 4;
  const int ncol0 = nbase + wv * 64;

  floatx4 acc[4][4];
#pragma unroll
  for (int i = 0; i < 4; ++i)
#pragma unroll
    for (int j = 0; j < 4; ++j) { acc[i][j][0] = 0.f; acc[i][j][1] = 0.f; acc[i][j][2] = 0.f; acc[i][j][3] = 0.f; }

  for (int kc = 0; kc < 8; ++kc) {
    {
      int r = tid >> 2;
      int cb = (tid & 3) * 16;
      size_t g = (size_t)(m0 + r) * DHID + kc * 64 + cb;
      uint4 a4 = *(const uint4*)(cur + g);
      if (prev) {
        uint4 p4 = *(const uint4*)(prev + g);
        a4.x = reluadd8(a4.x, p4.x); a4.y = reluadd8(a4.y, p4.y);
        a4.z = reluadd8(a4.z, p4.z); a4.w = reluadd8(a4.w, p4.w);
      } else {
        a4.x = relu8(a4.x); a4.y = relu8(a4.y);
        a4.z = relu8(a4.z); a4.w = relu8(a4.w);
      }
      u64c lo = ((u64c)a4.y << 32) | a4.x;
      u64c hi = ((u64c)a4.w << 32) | a4.z;
      *(u64c*)(&As[r][cb]) = lo;
      *(u64c*)(&As[r][cb + 8]) = hi;
    }
    __syncthreads();
#pragma unroll
    for (int kt = 0; kt < 2; ++kt) {
      int kg = kc * 64 + kt * 32 + q * 8;
      long bfr[4];
#pragma unroll
      for (int nt = 0; nt < 4; ++nt)
        bfr[nt] = *(const long*)(W + (size_t)(ncol0 + nt * 16 + c16) * DHID + kg);
      long afr[4];
#pragma unroll
      for (int mt = 0; mt < 4; ++mt)
        afr[mt] = *(const long*)(&As[mt * 16 + c16][kt * 32 + q * 8]);
#pragma unroll
      for (int nt = 0; nt < 4; ++nt)
#pragma unroll
        for (int mt = 0; mt < 4; ++mt)
          acc[nt][mt] = __builtin_amdgcn_mfma_f32_16x16x32_fp8_fp8(afr[mt], bfr[nt], acc[nt][mt], 0, 0, 0);
    }
    __syncthreads();
  }
  const int t = m0 >> 7;
  const int bb = (m0 & 127);
#pragma unroll
  for (int nt = 0; nt < 4; ++nt) {
    int col = ncol0 + nt * 16 + c16;
    float bv = bias[col];
#pragma unroll
    for (int mt = 0; mt < 4; ++mt) {
      int bbase = bb + mt * 16 + q * 4;
#pragma unroll
      for (int r = 0; r < 4; ++r)
        xw[((size_t)(bbase + r) * T_LEN + t) * 2048 + col] = ftof8(acc[nt][mt][r] + bv);
    }
  }
}

// ---------------------------------------------------------------------------
// LSTM scan R22 = R21 (verified) + WAVE-PARITY chunk swap.
// R21 was neutral: in-order issue + identical code + same barrier release
// phase-locks the two waves/SIMD (both in MFMA phase together, then both in
// VALU phase). Odd waves now run the chunk halves in swapped order (g,o
// first), so the parities occupy the matrix pipe with different halves and
// each parity's VALU lands during the other's MFMA issue. Pure reorder of
// verified arithmetic — identical values.
// ---------------------------------------------------------------------------
__launch_bounds__(512, 2)
__global__ void scan_kernel(const u8* __restrict__ whh, const u8* __restrict__ xw,
                            const float* __restrict__ h0, const float* __restrict__ c0,
                            u8* __restrict__ obuf) {
  __shared__ __align__(16) u8 hbuf[2][256];
  const int b   = blockIdx.x & 127;
  const int dir = blockIdx.x >> 7;
  const int tid = threadIdx.x;
  const int ln = tid & 63;
  const int wv = tid >> 6;              // 0..7
  const int c16 = ln & 15, q = ln >> 4;
  const int ntow = q & 1;
  const int col = wv * 32 + ntow * 16 + c16;   // lane's h-col (q pairs dup)
  const bool oddw = (wv & 1) != 0;

  // --- W -> B-frags [g][nt][kc]: 16 v8i = 128 regs, opaque-pinned ("+v") ---
  v8i wfr[4][2][2];
#pragma unroll
  for (int g = 0; g < 4; ++g)
#pragma unroll
    for (int nt = 0; nt < 2; ++nt)
#pragma unroll
      for (int kc = 0; kc < 2; ++kc) {
        const u8* p4 = whh + ((size_t)(dir * 1024 + g * 256 + wv * 32 + nt * 16 + c16)) * 256 + kc * 128 + q * 32;
        wfr[g][nt][kc] = frag_pair(*(const uint4*)p4, *(const uint4*)(p4 + 16));
      }
#pragma unroll
  for (int g = 0; g < 4; ++g)
#pragma unroll
    for (int nt = 0; nt < 2; ++nt)
#pragma unroll
      for (int kc = 0; kc < 2; ++kc)
        asm volatile("" : "+v"(wfr[g][nt][kc]));  // opaque def: no remat

  // --- h0 -> hbuf[0]; c state ---
  if (tid < 256) hbuf[0][tid] = ftof8(h0[((size_t)dir * BATCH + b) * H + tid]);
  float creg = c0[((size_t)dir * BATCH + b) * H + col];
  __syncthreads();

  // xw: [b][t][2048], block-private 1 KB per step
  const u8* xwt = xw + ((size_t)b * T_LEN + (dir ? T_LEN - 1 : 0)) * 2048 + dir * 1024;
  const ptrdiff_t xstep = (dir ? -1 : 1) * (ptrdiff_t)2048;
  u8* obt = obuf + ((size_t)(dir ? T_LEN - 1 : 0) * BATCH + b) * DHID + dir * H;
  const ptrdiff_t ostep = (dir ? -1 : 1) * (ptrdiff_t)(BATCH * DHID);

  u32 xb[4];
#pragma unroll
  for (int g = 0; g < 4; ++g) xb[g] = xwt[g * 256 + col];

  floatx4 z4;
  z4[0] = 0.f; z4[1] = 0.f; z4[2] = 0.f; z4[3] = 0.f;

  for (int s = 0; s < T_LEN; ++s) {
    const int p = s & 1, pn = p ^ 1;

    // A-frags: 2x ds_read_b128 each (broadcast within q-groups, conflict-free)
    const u8* hrow = &hbuf[p][q * 32];
    v8i hfr0 = frag_pair(*(const uint4*)(hrow), *(const uint4*)(hrow + 16));
    v8i hfr1 = frag_pair(*(const uint4*)(hrow + 128), *(const uint4*)(hrow + 144));

    float xg0 = f8tof(xb[0]), xg1 = f8tof(xb[1]);
    float xg2 = f8tof(xb[2]), xg3 = f8tof(xb[3]);
    if (s + 1 < T_LEN) {
      const u8* xn = xwt + xstep;
#pragma unroll
      for (int g = 0; g < 4; ++g) xb[g] = xn[g * 256 + col];
    }

    float cn, hbf;
    if (!oddw) {
      // ---- even waves: i,f MFMAs -> i,f exp -> g,o MFMAs -> rest ----
      floatx4 a00 = MFMA128(hfr0, wfr[0][0][0], z4);
      floatx4 a01 = MFMA128(hfr0, wfr[0][1][0], z4);
      floatx4 a10 = MFMA128(hfr0, wfr[1][0][0], z4);
      floatx4 a11 = MFMA128(hfr0, wfr[1][1][0], z4);
      a00 = MFMA128(hfr1, wfr[0][0][1], a00);
      a01 = MFMA128(hfr1, wfr[0][1][1], a01);
      a10 = MFMA128(hfr1, wfr[1][0][1], a10);
      a11 = MFMA128(hfr1, wfr[1][1][1], a11);
      __builtin_amdgcn_sched_barrier(0);
      float pre0 = (ntow ? a01[0] : a00[0]) + xg0;
      float pre1 = (ntow ? a11[0] : a10[0]) + xg1;
      float ei = __expf(-pre0);
      float ef = __expf(-pre1);
      __builtin_amdgcn_sched_barrier(0);
      floatx4 a20 = MFMA128(hfr0, wfr[2][0][0], z4);
      floatx4 a21 = MFMA128(hfr0, wfr[2][1][0], z4);
      floatx4 a30 = MFMA128(hfr0, wfr[3][0][0], z4);
      floatx4 a31 = MFMA128(hfr0, wfr[3][1][0], z4);
      a20 = MFMA128(hfr1, wfr[2][0][1], a20);
      a21 = MFMA128(hfr1, wfr[2][1][1], a21);
      a30 = MFMA128(hfr1, wfr[3][0][1], a30);
      a31 = MFMA128(hfr1, wfr[3][1][1], a31);
      __builtin_amdgcn_sched_barrier(0);
      float ig = __builtin_amdgcn_rcpf(1.0f + ei);
      float fg = __builtin_amdgcn_rcpf(1.0f + ef);
      float pre2 = (ntow ? a21[0] : a20[0]) + xg2;
      float pre3 = (ntow ? a31[0] : a30[0]) + xg3;
      float eg = __expf(-2.0f * pre2);
      float gg = 2.0f * __builtin_amdgcn_rcpf(1.0f + eg) - 1.0f;
      float eo = __expf(-pre3);
      float og = __builtin_amdgcn_rcpf(1.0f + eo);
      cn = fg * creg + ig * gg;
      float et = __expf(-2.0f * cn);
      float th = 2.0f * __builtin_amdgcn_rcpf(1.0f + et) - 1.0f;
      hbf = og * th;
    } else {
      // ---- odd waves: g,o MFMAs -> g,o exp -> i,f MFMAs -> rest ----
      floatx4 a20 = MFMA128(hfr0, wfr[2][0][0], z4);
      floatx4 a21 = MFMA128(hfr0, wfr[2][1][0], z4);
      floatx4 a30 = MFMA128(hfr0, wfr[3][0][0], z4);
      floatx4 a31 = MFMA128(hfr0, wfr[3][1][0], z4);
      a20 = MFMA128(hfr1, wfr[2][0][1], a20);
      a21 = MFMA128(hfr1, wfr[2][1][1], a21);
      a30 = MFMA128(hfr1, wfr[3][0][1], a30);
      a31 = MFMA128(hfr1, wfr[3][1][1], a31);
      __builtin_amdgcn_sched_barrier(0);
      float pre2 = (ntow ? a21[0] : a20[0]) + xg2;
      float pre3 = (ntow ? a31[0] : a30[0]) + xg3;
      float eg = __expf(-2.0f * pre2);
      float eo = __expf(-pre3);
      __builtin_amdgcn_sched_barrier(0);
      floatx4 a00 = MFMA128(hfr0, wfr[0][0][0], z4);
      floatx4 a01 = MFMA128(hfr0, wfr[0][1][0], z4);
      floatx4 a10 = MFMA128(hfr0, wfr[1][0][0], z4);
      floatx4 a11 = MFMA128(hfr0, wfr[1][1][0], z4);
      a00 = MFMA128(hfr1, wfr[0][0][1], a00);
      a01 = MFMA128(hfr1, wfr[0][1][1], a01);
      a10 = MFMA128(hfr1, wfr[1][0][1], a10);
      a11 = MFMA128(hfr1, wfr[1][1][1], a11);
      __builtin_amdgcn_sched_barrier(0);
      float gg = 2.0f * __builtin_amdgcn_rcpf(1.0f + eg) - 1.0f;
      float og = __builtin_amdgcn_rcpf(1.0f + eo);
      float pre0 = (ntow ? a01[0] : a00[0]) + xg0;
      float pre1 = (ntow ? a11[0] : a10[0]) + xg1;
      float ei = __expf(-pre0);
      float ig = __builtin_amdgcn_rcpf(1.0f + ei);
      float ef = __expf(-pre1);
      float fg = __builtin_amdgcn_rcpf(1.0f + ef);
      cn = fg * creg + ig * gg;
      float et = __expf(-2.0f * cn);
      float th = 2.0f * __builtin_amdgcn_rcpf(1.0f + et) - 1.0f;
      hbf = og * th;
    }
    creg = cn;
    u8 hb = ftof8(hbf);
    if (q < 2) {
      hbuf[pn][col] = hb;
      obt[col] = hb;                 // stays in flight across the raw barrier
    }
    wg_barrier_lds();

    xwt += xstep;
    obt += ostep;
  }
}

// ---------------------------------------------------------------------------
// FC: feats[16384][64] = out7(fp8)[16384][512] @ fcw^T + fc_b  (fp8 MFMA)
// ---------------------------------------------------------------------------
__launch_bounds__(256, 4)
__global__ void fc_kernel(const u8* __restrict__ A, const u8* __restrict__ W,
                          const float* __restrict__ fb, float* __restrict__ feats) {
  const int tid = threadIdx.x, wv = tid >> 6, ln = tid & 63;
  const int c16 = ln & 15, q = ln >> 4;
  const int m0 = blockIdx.x * 64 + wv * 16;
  floatx4 acc[4];
#pragma unroll
  for (int i = 0; i < 4; ++i) { acc[i][0] = 0.f; acc[i][1] = 0.f; acc[i][2] = 0.f; acc[i][3] = 0.f; }
#pragma unroll
  for (int kt = 0; kt < 16; ++kt) {
    long a = *(const long*)(A + (size_t)(m0 + c16) * DHID + kt * 32 + q * 8);
#pragma unroll
    for (int nt = 0; nt < 4; ++nt) {
      long b = *(const long*)(W + (size_t)(nt * 16 + c16) * DHID + kt * 32 + q * 8);
      acc[nt] = __builtin_amdgcn_mfma_f32_16x16x32_fp8_fp8(a, b, acc[nt], 0, 0, 0);
    }
  }
#pragma unroll
  for (int nt = 0; nt < 4; ++nt) {
    int n = nt * 16 + c16;
    if (n < NTAGS) {
      float bv = fb[n];
#pragma unroll
      for (int r = 0; r < 4; ++r)
        feats[(size_t)(m0 + q * 4 + r) * 64 + n] = acc[nt][r] + bv;
    }
  }
}

// ---------------------------------------------------------------------------
// CRF R22: alpha in registers (lane = tag). Per step the only cross-lane
// ops are ONE shfl (akm) + DPP reductions (VALU pipe) for the two live
// dense rows {0,1}:
//  - alpha[59] is DEAD: consumed only through NEG weights (t[:,59]=NEG in
//    the recurrence; t[59][59]=NEG in logZ) -> row-59 reduction dropped.
//  - alpha[58]: all transitions INTO 58 are NEG -> after t=0 it is -1e30;
//    modeled as the uniform scalar a58s = {0.0 at t=0, -1e30 after}
//    (contributions underflow to exactly 0.0 — bit-identical).
//  - nv0/nv1 computed as UNIFORM scalars via DPP max/sum + readlane ->
//    next step's phase A needs no shfl gathers for a0/a1.
// ---------------------------------------------------------------------------
__launch_bounds__(64, 1)
__global__ void crf_kernel(const float* __restrict__ feats, const float* __restrict__ trans,
                           const int* __restrict__ tags, float* __restrict__ out) {
  __shared__ float Tt[64][65];   // Tt[p][k] = trans[k*60+p], else -1e30
  const int b = blockIdx.x;
  const int ln = threadIdx.x;
  for (int i = ln; i < 64 * 65; i += 64) ((float*)Tt)[i] = -1e30f;
  __syncthreads();
  for (int i = ln; i < 3600; i += 64) Tt[i % 60][i / 60] = trans[i];
  __syncthreads();

  // gold path score
  float gsc = 0.f;
  for (int t = ln; t < T_LEN; t += 64) {
    int tg = tags[t * BATCH + b];
    int pv = (t == 0) ? START_TAG : tags[(t - 1) * BATCH + b];
    gsc += Tt[pv][tg] + feats[(size_t)(t * BATCH + b) * 64 + tg];
  }
#pragma unroll
  for (int off = 32; off > 0; off >>= 1) gsc += __shfl_down(gsc, off);
  if (ln == 0) gsc += Tt[tags[(T_LEN - 1) * BATCH + b]][STOP_TAG];

  // hoist t-invariant transition values
  const float t0k  = Tt[0][ln];
  const float t1k  = Tt[1][ln];
  const float tkm  = Tt[(ln - 1) & 63][ln];
  const float t58k = Tt[58][ln];
  const float tk0  = Tt[ln][0];
  const float tk1  = Tt[ln][1];
  const float tk59 = Tt[ln][59];

  // alpha recurrence, lane = tag
  float alpha = (ln == START_TAG) ? 0.f : NEGV;
  float a0s = NEGV, a1s = NEGV, a58s = 0.0f;   // scalars for next-step phase A
  const float* fbase = feats + (size_t)b * 64 + ln;
  const size_t fstride = (size_t)BATCH * 64;
  float fcur = fbase[0];
  for (int t = 0; t < T_LEN; ++t) {
    float fnext = (t + 1 < T_LEN) ? fbase[(size_t)(t + 1) * fstride] : 0.f;
    // gather (single LDS-pipe op; overlaps the DPP chains below)
    float akm = __shfl(alpha, ln - 1);
    // phase B (rows 0,1) on CURRENT alpha, all-DPP
    float w0 = alpha + tk0;
    float w1 = alpha + tk1;
    float M0 = dpp_max64(w0);
    float M1 = dpp_max64(w1);
    float e0 = __expf(w0 - M0);
    float e1 = __expf(w1 - M1);
    float S0 = dpp_sum64(e0);
    float S1 = dpp_sum64(e1);
    float f0s = __int_as_float(__builtin_amdgcn_readlane(__float_as_int(fcur), 0));
    float f1s = __int_as_float(__builtin_amdgcn_readlane(__float_as_int(fcur), 1));
    float nv0 = M0 + __logf(S0) + f0s;
    float nv1 = M1 + __logf(S1) + f1s;
    // phase A: sparse 4-term LSE (lanes 2..57)
    float v0 = a0s + t0k;
    float v1 = a1s + t1k;
    float v2 = (ln >= 3) ? (akm + tkm) : -1e30f;
    float v3 = a58s + t58k;
    float mA = fmaxf(fmaxf(v0, v1), fmaxf(v2, v3));
    float sA = ((__expf(v0 - mA) + __expf(v1 - mA)) + __expf(v2 - mA)) + __expf(v3 - mA);
    float nvA = mA + __logf(sA) + fcur;
    // update
    float nv = nvA;
    if (ln == 0) nv = nv0;
    else if (ln == 1) nv = nv1;
    else if (ln >= 58) nv = -1e30f;
    alpha = nv;
    a0s = nv0; a1s = nv1; a58s = -1e30f;
    fcur = fnext;
  }

  // logZ = LSE(alpha + trans[STOP][p])
  float v = alpha + tk59;
  float mm = v;
#pragma unroll
  for (int off = 32; off > 0; off >>= 1) mm = fmaxf(mm, __shfl_xor(mm, off));
  float es = __expf(v - mm);
#pragma unroll
  for (int off = 32; off > 0; off >>= 1) es += __shfl_xor(es, off);
  if (ln == 0) out[b] = mm + __logf(es) - gsc;
}

// ---------------------------------------------------------------------------
extern "C" void kernel_launch(void* const* d_in, const int* in_sizes, int n_in,
                              void* d_out, int out_size, void* d_ws, size_t ws_size,
                              hipStream_t stream) {
  (void)in_sizes; (void)n_in; (void)out_size; (void)ws_size;
  const float* sent  = (const float*)d_in[0];
  const int*   tags  = (const int*)d_in[1];
  const float* wih1  = (const float*)d_in[2];
  const float* whh1  = (const float*)d_in[3];
  const float* b1    = (const float*)d_in[4];
  const float* wih   = (const float*)d_in[5];
  const float* whh   = (const float*)d_in[6];
  const float* bias  = (const float*)d_in[7];
  const float* fcw   = (const float*)d_in[8];
  const float* fcb   = (const float*)d_in[9];
  const float* h0    = (const float*)d_in[10];
  const float* c0    = (const float*)d_in[11];
  const float* trans = (const float*)d_in[12];
  float* out = (float*)d_out;

  char* ws = (char*)d_ws;
  size_t off = 0;
  auto alloc = [&](size_t bytes) -> void* {
    void* p = ws + off;
    off = (off + bytes + 255) & ~(size_t)255;
    return p;
  };
  u8* whh_f8 = (u8*)alloc((size_t)7 * 2 * 1024 * 256);
  u8* wih_f8 = (u8*)alloc((size_t)6 * 2 * 1024 * 512);
  u8* fcw_f8 = (u8*)alloc((size_t)64 * 512);
  u8* xw     = (u8*)alloc((size_t)16384 * 2048);
  u8* ob[3];
  for (int i = 0; i < 3; ++i) ob[i] = (u8*)alloc((size_t)16384 * 512);
  float* feats = (float*)alloc((size_t)16384 * 64 * 4);

  hipLaunchKernelGGL(pack_kernel, dim3(4096), dim3(256), 0, stream,
                     whh1, whh, wih, fcw, whh_f8, wih_f8, fcw_f8);
  hipLaunchKernelGGL(xw1_kernel, dim3(32768), dim3(256), 0, stream, sent, wih1, b1, xw);
  hipLaunchKernelGGL(scan_kernel, dim3(256), dim3(512), 0, stream,
                     whh_f8, xw, h0, c0, ob[0]);
  for (int L = 1; L < 7; ++L) {
    const u8* curb = ob[(L - 1) % 3];
    const u8* prevb = (L >= 2) ? ob[(L - 2) % 3] : nullptr;
    hipLaunchKernelGGL(gemm_xw_kernel, dim3(8, 256), dim3(256), 0, stream,
                       curb, prevb, wih_f8 + (size_t)(L - 1) * 2 * 1024 * 512,
                       bias + (size_t)(L - 1) * 2048, xw);
    hipLaunchKernelGGL(scan_kernel, dim3(256), dim3(512), 0, stream,
                       whh_f8 + (size_t)L * 2 * 1024 * 256, xw,
                       h0 + (size_t)L * 2 * 128 * 256, c0 + (size_t)L * 2 * 128 * 256,
                       ob[L % 3]);
  }
  hipLaunchKernelGGL(fc_kernel, dim3(256), dim3(256), 0, stream, ob[0], fcw_f8, fcb, feats);
  hipLaunchKernelGGL(crf_kernel, dim3(128), dim3(64), 0, stream, feats, trans, tags, out);
}

// Round 9
// 1386.466 us; speedup vs baseline: 1.0470x; 1.0127x over previous
//
#include <hip/hip_runtime.h>
#include <stdint.h>

#define T_LEN 128
#define BATCH 128
#define DHID 512
#define H 256
#define NTAGS 60
#define START_TAG 58
#define STOP_TAG 59
#define NEGV -10000.0f

typedef __attribute__((ext_vector_type(4))) float floatx4;
typedef __attribute__((ext_vector_type(2))) float floatx2;
typedef __attribute__((ext_vector_type(8))) int v8i;
typedef unsigned short u16;
typedef unsigned char u8;
typedef unsigned int u32;
typedef unsigned long long u64c;

#define SCALE1 0x7F7F7F7F  // E8M0 = 1.0 in every byte

// HW fp8 (e4m3) conversions
__device__ __forceinline__ floatx4 f8x4tof(u32 v) {
  floatx2 lo = __builtin_amdgcn_cvt_pk_f32_fp8((int)v, false);
  floatx2 hi = __builtin_amdgcn_cvt_pk_f32_fp8((int)v, true);
  floatx4 r;
  r[0] = lo[0]; r[1] = lo[1]; r[2] = hi[0]; r[3] = hi[1];
  return r;
}
__device__ __forceinline__ float f8tof(u32 v) {
  floatx2 lo = __builtin_amdgcn_cvt_pk_f32_fp8((int)(v & 0xff), false);
  return lo[0];
}
__device__ __forceinline__ u8 ftof8(float f) {
  return (u8)(__builtin_amdgcn_cvt_pk_fp8_f32(f, f, 0, false) & 0xff);
}
__device__ __forceinline__ u32 pk4f8(float a, float b, float c, float d) {
  int o = __builtin_amdgcn_cvt_pk_fp8_f32(a, b, 0, false);
  o = __builtin_amdgcn_cvt_pk_fp8_f32(c, d, o, true);
  return (u32)o;
}
__device__ __forceinline__ float sigx(float x) {
  float e = __expf(-x);
  return __builtin_amdgcn_rcpf(1.0f + e);
}
__device__ __forceinline__ float tanhx(float x) {
  float e = __expf(-2.0f * x);
  return 2.0f * __builtin_amdgcn_rcpf(1.0f + e) - 1.0f;
}
__device__ __forceinline__ u32 relu8(u32 a) {
  u32 m = (a & 0x80808080u) >> 7;
  m *= 255u;
  return a & ~m;
}
__device__ __forceinline__ u32 reluadd8(u32 a, u32 b) {
  floatx4 av = f8x4tof(relu8(a));
  floatx4 bv = f8x4tof(relu8(b));
  return pk4f8(av[0] + bv[0], av[1] + bv[1], av[2] + bv[2], av[3] + bv[3]);
}
// 32-byte fragment builders
__device__ __forceinline__ v8i frag_pair(uint4 a, uint4 b) {
  union { uint4 q[2]; v8i v; } u;
  u.q[0] = a; u.q[1] = b;
  return u.v;
}
#define MFMA128(a, b, c) \
  __builtin_amdgcn_mfma_scale_f32_16x16x128_f8f6f4((a), (b), (c), 0, 0, 0, SCALE1, 0, SCALE1)

// Raw workgroup barrier: LDS-visibility only (R17/R19/R20/R21-verified).
__device__ __forceinline__ void wg_barrier_lds() {
  asm volatile("s_waitcnt lgkmcnt(0)" ::: "memory");
  __builtin_amdgcn_s_barrier();
  __builtin_amdgcn_sched_barrier(0);
}

// --- DPP full-wave reductions (VALU pipe, ~10 cyc/level vs ~120 for shfl) ---
__device__ __forceinline__ float dpp_max64(float v) {
  int t;
#define DMAXSTEP(CTRL)                                                         \
  t = __builtin_amdgcn_update_dpp(__float_as_int(-1e30f), __float_as_int(v),   \
                                  (CTRL), 0xf, 0xf, false);                    \
  v = fmaxf(v, __int_as_float(t));
  DMAXSTEP(0x111) DMAXSTEP(0x112) DMAXSTEP(0x114) DMAXSTEP(0x118)
  DMAXSTEP(0x142) DMAXSTEP(0x143)
#undef DMAXSTEP
  return __int_as_float(__builtin_amdgcn_readlane(__float_as_int(v), 63));
}
__device__ __forceinline__ float dpp_sum64(float v) {
  int t;
#define DADDSTEP(CTRL)                                                         \
  t = __builtin_amdgcn_update_dpp(__float_as_int(0.0f), __float_as_int(v),     \
                                  (CTRL), 0xf, 0xf, false);                    \
  v = v + __int_as_float(t);
  DADDSTEP(0x111) DADDSTEP(0x112) DADDSTEP(0x114) DADDSTEP(0x118)
  DADDSTEP(0x142) DADDSTEP(0x143)
#undef DADDSTEP
  return __int_as_float(__builtin_amdgcn_readlane(__float_as_int(v), 63));
}

// ---------------------------------------------------------------------------
// Pack weights -> fp8: whh [7][2][1024][256], wih [6][2][1024][512], fcw [64][512].
// ---------------------------------------------------------------------------
__global__ void pack_kernel(const float* __restrict__ whh1, const float* __restrict__ whh,
                            const float* __restrict__ wih, const float* __restrict__ fcw,
                            u8* __restrict__ whh_f8, u8* __restrict__ wih_f8,
                            u8* __restrict__ fcw_f8) {
  const int n_whh1 = 2 * 1024 * 256;
  const int n_whh  = 6 * 2 * 1024 * 256;
  const int n_wih  = 6 * 2 * 1024 * 512;
  const int n_fcw  = 64 * 512;
  const int total = n_whh1 + n_whh + n_wih + n_fcw;
  for (int i = blockIdx.x * blockDim.x + threadIdx.x; i < total; i += gridDim.x * blockDim.x) {
    if (i < n_whh1) {
      whh_f8[i] = ftof8(whh1[i]);
    } else if (i < n_whh1 + n_whh) {
      whh_f8[i] = ftof8(whh[i - n_whh1]);
    } else if (i < n_whh1 + n_whh + n_wih) {
      int j = i - n_whh1 - n_whh;
      wih_f8[j] = ftof8(wih[j]);
    } else {
      int j = i - n_whh1 - n_whh - n_wih;
      int row = j >> 9;
      fcw_f8[j] = (row < NTAGS) ? ftof8(fcw[j]) : (u8)0;
    }
  }
}

// ---------------------------------------------------------------------------
// Layer-1 xw (Din=3), fp8. Layout: xw[b][t][2048 cols] batch-major.
// ---------------------------------------------------------------------------
__global__ void xw1_kernel(const float* __restrict__ sent, const float* __restrict__ wih1,
                           const float* __restrict__ b1, u8* __restrict__ xw) {
  int u = blockIdx.x * blockDim.x + threadIdx.x;  // 128b * 128t * 512 u32
  int cq = u & 511;
  int t = (u >> 9) & 127;
  int b = u >> 16;
  int col0 = cq * 4;
  const float* x = sent + ((size_t)t * BATCH + b) * 3;
  float x0 = x[0], x1 = x[1], x2 = x[2];
  float o[4];
#pragma unroll
  for (int j = 0; j < 4; ++j) {
    const float* w = wih1 + (size_t)(col0 + j) * 3;
    o[j] = b1[col0 + j] + x0 * w[0] + x1 * w[1] + x2 * w[2];
  }
  *(u32*)(xw + ((size_t)b * T_LEN + t) * 2048 + col0) = pk4f8(o[0], o[1], o[2], o[3]);
}

// ---------------------------------------------------------------------------
// xw GEMM layers 2..7 (plain fp8 K=32 MFMA — measured fastest).
// ---------------------------------------------------------------------------
__launch_bounds__(256, 4)
__global__ void gemm_xw_kernel(const u8* __restrict__ cur, const u8* __restrict__ prev,
                               const u8* __restrict__ W, const float* __restrict__ bias,
                               u8* __restrict__ xw) {
  __shared__ __align__(16) u8 As[64][72];
  const int nbase = blockIdx.x * 256;
  const int m0 = blockIdx.y * 64;
  const int tid = threadIdx.x;
  const int wv = tid >> 6, ln = tid & 63;
  const int c16 = ln & 15, q = ln >> 4;
  const int ncol0 = nbase + wv * 64;

  floatx4 acc[4][4];
#pragma unroll
  for (int i = 0; i < 4; ++i)
#pragma unroll
    for (int j = 0; j < 4; ++j) { acc[i][j][0] = 0.f; acc[i][j][1] = 0.f; acc[i][j][2] = 0.f; acc[i][j][3] = 0.f; }

  for (int kc = 0; kc < 8; ++kc) {
    {
      int r = tid >> 2;
      int cb = (tid & 3) * 16;
      size_t g = (size_t)(m0 + r) * DHID + kc * 64 + cb;
      uint4 a4 = *(const uint4*)(cur + g);
      if (prev) {
        uint4 p4 = *(const uint4*)(prev + g);
        a4.x = reluadd8(a4.x, p4.x); a4.y = reluadd8(a4.y, p4.y);
        a4.z = reluadd8(a4.z, p4.z); a4.w = reluadd8(a4.w, p4.w);
      } else {
        a4.x = relu8(a4.x); a4.y = relu8(a4.y);
        a4.z = relu8(a4.z); a4.w = relu8(a4.w);
      }
      u64c lo = ((u64c)a4.y << 32) | a4.x;
      u64c hi = ((u64c)a4.w << 32) | a4.z;
      *(u64c*)(&As[r][cb]) = lo;
      *(u64c*)(&As[r][cb + 8]) = hi;
    }
    __syncthreads();
#pragma unroll
    for (int kt = 0; kt < 2; ++kt) {
      int kg = kc * 64 + kt * 32 + q * 8;
      long bfr[4];
#pragma unroll
      for (int nt = 0; nt < 4; ++nt)
        bfr[nt] = *(const long*)(W + (size_t)(ncol0 + nt * 16 + c16) * DHID + kg);
      long afr[4];
#pragma unroll
      for (int mt = 0; mt < 4; ++mt)
        afr[mt] = *(const long*)(&As[mt * 16 + c16][kt * 32 + q * 8]);
#pragma unroll
      for (int nt = 0; nt < 4; ++nt)
#pragma unroll
        for (int mt = 0; mt < 4; ++mt)
          acc[nt][mt] = __builtin_amdgcn_mfma_f32_16x16x32_fp8_fp8(afr[mt], bfr[nt], acc[nt][mt], 0, 0, 0);
    }
    __syncthreads();
  }
  const int t = m0 >> 7;
  const int bb = (m0 & 127);
#pragma unroll
  for (int nt = 0; nt < 4; ++nt) {
    int col = ncol0 + nt * 16 + c16;
    float bv = bias[col];
#pragma unroll
    for (int mt = 0; mt < 4; ++mt) {
      int bbase = bb + mt * 16 + q * 4;
#pragma unroll
      for (int r = 0; r < 4; ++r)
        xw[((size_t)(bbase + r) * T_LEN + t) * 2048 + col] = ftof8(acc[nt][mt][r] + bv);
    }
  }
}

// ---------------------------------------------------------------------------
// LSTM scan R23 = R21 exact (best-measured: 117.1 µs, 92 VGPR). Grid 256
// (dir*128+b), block 512 = 8 waves = 2 waves/SIMD. R22's parity swap
// REVERTED (+5 µs, +8 VGPR, no desync — R20/R21/R22 triple-measurement
// shows step time = MFMA drain (1107 cyc/SIMD) + dependent gate tail +
// barrier/LDS latency, schedule-insensitive; ~117 µs is this structure's
// floor). Chunked schedule: {8 MFMA i,f} |SB| {i,f exp} |SB| {8 MFMA g,o}
// |SB| {rest}. Zero C-init + post-MFMA xw add; raw lgkmcnt-only barrier.
// ---------------------------------------------------------------------------
__launch_bounds__(512, 2)
__global__ void scan_kernel(const u8* __restrict__ whh, const u8* __restrict__ xw,
                            const float* __restrict__ h0, const float* __restrict__ c0,
                            u8* __restrict__ obuf) {
  __shared__ __align__(16) u8 hbuf[2][256];
  const int b   = blockIdx.x & 127;
  const int dir = blockIdx.x >> 7;
  const int tid = threadIdx.x;
  const int ln = tid & 63;
  const int wv = tid >> 6;              // 0..7
  const int c16 = ln & 15, q = ln >> 4;
  const int ntow = q & 1;
  const int col = wv * 32 + ntow * 16 + c16;   // lane's h-col (q pairs dup)

  // --- W -> B-frags [g][nt][kc]: 16 v8i = 128 regs, opaque-pinned ("+v") ---
  v8i wfr[4][2][2];
#pragma unroll
  for (int g = 0; g < 4; ++g)
#pragma unroll
    for (int nt = 0; nt < 2; ++nt)
#pragma unroll
      for (int kc = 0; kc < 2; ++kc) {
        const u8* p4 = whh + ((size_t)(dir * 1024 + g * 256 + wv * 32 + nt * 16 + c16)) * 256 + kc * 128 + q * 32;
        wfr[g][nt][kc] = frag_pair(*(const uint4*)p4, *(const uint4*)(p4 + 16));
      }
#pragma unroll
  for (int g = 0; g < 4; ++g)
#pragma unroll
    for (int nt = 0; nt < 2; ++nt)
#pragma unroll
      for (int kc = 0; kc < 2; ++kc)
        asm volatile("" : "+v"(wfr[g][nt][kc]));  // opaque def: no remat

  // --- h0 -> hbuf[0]; c state ---
  if (tid < 256) hbuf[0][tid] = ftof8(h0[((size_t)dir * BATCH + b) * H + tid]);
  float creg = c0[((size_t)dir * BATCH + b) * H + col];
  __syncthreads();

  // xw: [b][t][2048], block-private 1 KB per step
  const u8* xwt = xw + ((size_t)b * T_LEN + (dir ? T_LEN - 1 : 0)) * 2048 + dir * 1024;
  const ptrdiff_t xstep = (dir ? -1 : 1) * (ptrdiff_t)2048;
  u8* obt = obuf + ((size_t)(dir ? T_LEN - 1 : 0) * BATCH + b) * DHID + dir * H;
  const ptrdiff_t ostep = (dir ? -1 : 1) * (ptrdiff_t)(BATCH * DHID);

  u32 xb[4];
#pragma unroll
  for (int g = 0; g < 4; ++g) xb[g] = xwt[g * 256 + col];

  floatx4 z4;
  z4[0] = 0.f; z4[1] = 0.f; z4[2] = 0.f; z4[3] = 0.f;

  for (int s = 0; s < T_LEN; ++s) {
    const int p = s & 1, pn = p ^ 1;

    // A-frags: 2x ds_read_b128 each (broadcast within q-groups, conflict-free)
    const u8* hrow = &hbuf[p][q * 32];
    v8i hfr0 = frag_pair(*(const uint4*)(hrow), *(const uint4*)(hrow + 16));
    v8i hfr1 = frag_pair(*(const uint4*)(hrow + 128), *(const uint4*)(hrow + 144));

    float xg0 = f8tof(xb[0]), xg1 = f8tof(xb[1]);
    float xg2 = f8tof(xb[2]), xg3 = f8tof(xb[3]);
    if (s + 1 < T_LEN) {
      const u8* xn = xwt + xstep;
#pragma unroll
      for (int g = 0; g < 4; ++g) xb[g] = xn[g * 256 + col];
    }

    // ---- chunk A: 8 MFMA for gates i,f ----
    floatx4 a00 = MFMA128(hfr0, wfr[0][0][0], z4);
    floatx4 a01 = MFMA128(hfr0, wfr[0][1][0], z4);
    floatx4 a10 = MFMA128(hfr0, wfr[1][0][0], z4);
    floatx4 a11 = MFMA128(hfr0, wfr[1][1][0], z4);
    a00 = MFMA128(hfr1, wfr[0][0][1], a00);
    a01 = MFMA128(hfr1, wfr[0][1][1], a01);
    a10 = MFMA128(hfr1, wfr[1][0][1], a10);
    a11 = MFMA128(hfr1, wfr[1][1][1], a11);
    __builtin_amdgcn_sched_barrier(0);

    // ---- gate VALU for i,f ----
    float pre0 = (ntow ? a01[0] : a00[0]) + xg0;
    float pre1 = (ntow ? a11[0] : a10[0]) + xg1;
    float ei = __expf(-pre0);
    float ef = __expf(-pre1);
    __builtin_amdgcn_sched_barrier(0);

    // ---- chunk B: 8 MFMA for gates g,o ----
    floatx4 a20 = MFMA128(hfr0, wfr[2][0][0], z4);
    floatx4 a21 = MFMA128(hfr0, wfr[2][1][0], z4);
    floatx4 a30 = MFMA128(hfr0, wfr[3][0][0], z4);
    floatx4 a31 = MFMA128(hfr0, wfr[3][1][0], z4);
    a20 = MFMA128(hfr1, wfr[2][0][1], a20);
    a21 = MFMA128(hfr1, wfr[2][1][1], a21);
    a30 = MFMA128(hfr1, wfr[3][0][1], a30);
    a31 = MFMA128(hfr1, wfr[3][1][1], a31);
    __builtin_amdgcn_sched_barrier(0);

    // ---- remaining gate chain ----
    float ig = __builtin_amdgcn_rcpf(1.0f + ei);
    float fg = __builtin_amdgcn_rcpf(1.0f + ef);
    float pre2 = (ntow ? a21[0] : a20[0]) + xg2;
    float pre3 = (ntow ? a31[0] : a30[0]) + xg3;
    float eg = __expf(-2.0f * pre2);
    float gg = 2.0f * __builtin_amdgcn_rcpf(1.0f + eg) - 1.0f;
    float eo = __expf(-pre3);
    float og = __builtin_amdgcn_rcpf(1.0f + eo);
    float cn = fg * creg + ig * gg;
    creg = cn;
    float et = __expf(-2.0f * cn);
    float th = 2.0f * __builtin_amdgcn_rcpf(1.0f + et) - 1.0f;
    u8 hb = ftof8(og * th);
    if (q < 2) {
      hbuf[pn][col] = hb;
      obt[col] = hb;                 // stays in flight across the raw barrier
    }
    wg_barrier_lds();

    xwt += xstep;
    obt += ostep;
  }
}

// ---------------------------------------------------------------------------
// FC: feats[16384][64] = out7(fp8)[16384][512] @ fcw^T + fc_b  (fp8 MFMA)
// ---------------------------------------------------------------------------
__launch_bounds__(256, 4)
__global__ void fc_kernel(const u8* __restrict__ A, const u8* __restrict__ W,
                          const float* __restrict__ fb, float* __restrict__ feats) {
  const int tid = threadIdx.x, wv = tid >> 6, ln = tid & 63;
  const int c16 = ln & 15, q = ln >> 4;
  const int m0 = blockIdx.x * 64 + wv * 16;
  floatx4 acc[4];
#pragma unroll
  for (int i = 0; i < 4; ++i) { acc[i][0] = 0.f; acc[i][1] = 0.f; acc[i][2] = 0.f; acc[i][3] = 0.f; }
#pragma unroll
  for (int kt = 0; kt < 16; ++kt) {
    long a = *(const long*)(A + (size_t)(m0 + c16) * DHID + kt * 32 + q * 8);
#pragma unroll
    for (int nt = 0; nt < 4; ++nt) {
      long b = *(const long*)(W + (size_t)(nt * 16 + c16) * DHID + kt * 32 + q * 8);
      acc[nt] = __builtin_amdgcn_mfma_f32_16x16x32_fp8_fp8(a, b, acc[nt], 0, 0, 0);
    }
  }
#pragma unroll
  for (int nt = 0; nt < 4; ++nt) {
    int n = nt * 16 + c16;
    if (n < NTAGS) {
      float bv = fb[n];
#pragma unroll
      for (int r = 0; r < 4; ++r)
        feats[(size_t)(m0 + q * 4 + r) * 64 + n] = acc[nt][r] + bv;
    }
  }
}

// ---------------------------------------------------------------------------
// CRF R22 (verified): alpha in registers (lane = tag); one shfl + DPP
// reductions per step; rows 58/59 dead-path shortcuts (bit-identical).
// ---------------------------------------------------------------------------
__launch_bounds__(64, 1)
__global__ void crf_kernel(const float* __restrict__ feats, const float* __restrict__ trans,
                           const int* __restrict__ tags, float* __restrict__ out) {
  __shared__ float Tt[64][65];   // Tt[p][k] = trans[k*60+p], else -1e30
  const int b = blockIdx.x;
  const int ln = threadIdx.x;
  for (int i = ln; i < 64 * 65; i += 64) ((float*)Tt)[i] = -1e30f;
  __syncthreads();
  for (int i = ln; i < 3600; i += 64) Tt[i % 60][i / 60] = trans[i];
  __syncthreads();

  // gold path score
  float gsc = 0.f;
  for (int t = ln; t < T_LEN; t += 64) {
    int tg = tags[t * BATCH + b];
    int pv = (t == 0) ? START_TAG : tags[(t - 1) * BATCH + b];
    gsc += Tt[pv][tg] + feats[(size_t)(t * BATCH + b) * 64 + tg];
  }
#pragma unroll
  for (int off = 32; off > 0; off >>= 1) gsc += __shfl_down(gsc, off);
  if (ln == 0) gsc += Tt[tags[(T_LEN - 1) * BATCH + b]][STOP_TAG];

  // hoist t-invariant transition values
  const float t0k  = Tt[0][ln];
  const float t1k  = Tt[1][ln];
  const float tkm  = Tt[(ln - 1) & 63][ln];
  const float t58k = Tt[58][ln];
  const float tk0  = Tt[ln][0];
  const float tk1  = Tt[ln][1];
  const float tk59 = Tt[ln][59];

  // alpha recurrence, lane = tag
  float alpha = (ln == START_TAG) ? 0.f : NEGV;
  float a0s = NEGV, a1s = NEGV, a58s = 0.0f;   // scalars for next-step phase A
  const float* fbase = feats + (size_t)b * 64 + ln;
  const size_t fstride = (size_t)BATCH * 64;
  float fcur = fbase[0];
  for (int t = 0; t < T_LEN; ++t) {
    float fnext = (t + 1 < T_LEN) ? fbase[(size_t)(t + 1) * fstride] : 0.f;
    float akm = __shfl(alpha, ln - 1);
    // phase B (rows 0,1) on CURRENT alpha, all-DPP
    float w0 = alpha + tk0;
    float w1 = alpha + tk1;
    float M0 = dpp_max64(w0);
    float M1 = dpp_max64(w1);
    float e0 = __expf(w0 - M0);
    float e1 = __expf(w1 - M1);
    float S0 = dpp_sum64(e0);
    float S1 = dpp_sum64(e1);
    float f0s = __int_as_float(__builtin_amdgcn_readlane(__float_as_int(fcur), 0));
    float f1s = __int_as_float(__builtin_amdgcn_readlane(__float_as_int(fcur), 1));
    float nv0 = M0 + __logf(S0) + f0s;
    float nv1 = M1 + __logf(S1) + f1s;
    // phase A: sparse 4-term LSE (lanes 2..57)
    float v0 = a0s + t0k;
    float v1 = a1s + t1k;
    float v2 = (ln >= 3) ? (akm + tkm) : -1e30f;
    float v3 = a58s + t58k;
    float mA = fmaxf(fmaxf(v0, v1), fmaxf(v2, v3));
    float sA = ((__expf(v0 - mA) + __expf(v1 - mA)) + __expf(v2 - mA)) + __expf(v3 - mA);
    float nvA = mA + __logf(sA) + fcur;
    // update
    float nv = nvA;
    if (ln == 0) nv = nv0;
    else if (ln == 1) nv = nv1;
    else if (ln >= 58) nv = -1e30f;
    alpha = nv;
    a0s = nv0; a1s = nv1; a58s = -1e30f;
    fcur = fnext;
  }

  // logZ = LSE(alpha + trans[STOP][p])
  float v = alpha + tk59;
  float mm = v;
#pragma unroll
  for (int off = 32; off > 0; off >>= 1) mm = fmaxf(mm, __shfl_xor(mm, off));
  float es = __expf(v - mm);
#pragma unroll
  for (int off = 32; off > 0; off >>= 1) es += __shfl_xor(es, off);
  if (ln == 0) out[b] = mm + __logf(es) - gsc;
}

// ---------------------------------------------------------------------------
extern "C" void kernel_launch(void* const* d_in, const int* in_sizes, int n_in,
                              void* d_out, int out_size, void* d_ws, size_t ws_size,
                              hipStream_t stream) {
  (void)in_sizes; (void)n_in; (void)out_size; (void)ws_size;
  const float* sent  = (const float*)d_in[0];
  const int*   tags  = (const int*)d_in[1];
  const float* wih1  = (const float*)d_in[2];
  const float* whh1  = (const float*)d_in[3];
  const float* b1    = (const float*)d_in[4];
  const float* wih   = (const float*)d_in[5];
  const float* whh   = (const float*)d_in[6];
  const float* bias  = (const float*)d_in[7];
  const float* fcw   = (const float*)d_in[8];
  const float* fcb   = (const float*)d_in[9];
  const float* h0    = (const float*)d_in[10];
  const float* c0    = (const float*)d_in[11];
  const float* trans = (const float*)d_in[12];
  float* out = (float*)d_out;

  char* ws = (char*)d_ws;
  size_t off = 0;
  auto alloc = [&](size_t bytes) -> void* {
    void* p = ws + off;
    off = (off + bytes + 255) & ~(size_t)255;
    return p;
  };
  u8* whh_f8 = (u8*)alloc((size_t)7 * 2 * 1024 * 256);
  u8* wih_f8 = (u8*)alloc((size_t)6 * 2 * 1024 * 512);
  u8* fcw_f8 = (u8*)alloc((size_t)64 * 512);
  u8* xw     = (u8*)alloc((size_t)16384 * 2048);
  u8* ob[3];
  for (int i = 0; i < 3; ++i) ob[i] = (u8*)alloc((size_t)16384 * 512);
  float* feats = (float*)alloc((size_t)16384 * 64 * 4);

  hipLaunchKernelGGL(pack_kernel, dim3(4096), dim3(256), 0, stream,
                     whh1, whh, wih, fcw, whh_f8, wih_f8, fcw_f8);
  hipLaunchKernelGGL(xw1_kernel, dim3(32768), dim3(256), 0, stream, sent, wih1, b1, xw);
  hipLaunchKernelGGL(scan_kernel, dim3(256), dim3(512), 0, stream,
                     whh_f8, xw, h0, c0, ob[0]);
  for (int L = 1; L < 7; ++L) {
    const u8* curb = ob[(L - 1) % 3];
    const u8* prevb = (L >= 2) ? ob[(L - 2) % 3] : nullptr;
    hipLaunchKernelGGL(gemm_xw_kernel, dim3(8, 256), dim3(256), 0, stream,
                       curb, prevb, wih_f8 + (size_t)(L - 1) * 2 * 1024 * 512,
                       bias + (size_t)(L - 1) * 2048, xw);
    hipLaunchKernelGGL(scan_kernel, dim3(256), dim3(512), 0, stream,
                       whh_f8 + (size_t)L * 2 * 1024 * 256, xw,
                       h0 + (size_t)L * 2 * 128 * 256, c0 + (size_t)L * 2 * 128 * 256,
                       ob[L % 3]);
  }
  hipLaunchKernelGGL(fc_kernel, dim3(256), dim3(256), 0, stream, ob[0], fcw_f8, fcb, feats);
  hipLaunchKernelGGL(crf_kernel, dim3(128), dim3(64), 0, stream, feats, trans, tags, out);
}